// Round 1
// 161.700 us; speedup vs baseline: 1.0319x; 1.0319x over previous
//
#include <hip/hip_runtime.h>
#include <hip/hip_bf16.h>

#define BB 4
#define HH 160
#define WW 160
#define HWD (HH * WW)                   // 25600
#define OUT_ELEMS (BB * 64 * HWD)       // 6,553,600
#define OFF_ELEMS (BB * 18 * HWD)       // 1,843,200
#define EPSBN 1e-5f
#define CHSTRIDE (8 * HWD)              // 8-channel chunk stride
#define NSLOT 256                       // BN partial slots per channel-stat

typedef __attribute__((ext_vector_type(8))) short bf16x8;
typedef __attribute__((ext_vector_type(4))) float f32x4;

__device__ inline unsigned pack2bf(float a, float b) {
  __hip_bfloat162 h2 = __float22bfloat162_rn(float2{a, b});
  unsigned u;
  __builtin_memcpy(&u, &h2, 4);
  return u;
}
__device__ inline unsigned short bf16bits(float a) {
  __hip_bfloat16 h = __float2bfloat16(a);
  unsigned short u;
  __builtin_memcpy(&u, &h, 2);
  return u;
}

// XCD-slab tile mapping: blk%8 = XCD (HW round-robin); each XCD owns 200
// spatially-contiguous tiles (an 80-pixel-row band) so halo re-reads and
// the offconv->dconv handoff stay inside one 4MB L2.
__device__ inline void tile_map(int blk, int& b, int& ty0, int& tx0) {
  int t = (blk & 7) * 200 + (blk >> 3);
  b = t / 400;
  int r = t % 400;
  ty0 = (r / 10) * 4;
  tx0 = (r % 10) * 16;
}

// ---------------------------------------------------------------------------
// prep: prepacked MFMA B-fragments (K permuted to kappa = tap*8 + ch within
// each 8-ch chunk, 96-padded; taps 9..11 zero) + zero the BN partial slots.
// ---------------------------------------------------------------------------
__global__ void prep_kernel(const float* __restrict__ cw,
                            const float* __restrict__ ow,
                            unsigned short* __restrict__ Bp,
                            unsigned short* __restrict__ B2p,
                            float* __restrict__ part) {
  int i = blockIdx.x * 256 + threadIdx.x;
  if (i < 32768) part[i] = 0.f;
  if (i < 49152) {                      // dconv weights conv_w[n][c][t], nt 0..3
    int j = i & 7, l = (i >> 3) & 63, rest = i >> 9;
    int ki = rest % 24, nt = rest / 24;
    int kp = ki * 32 + ((l >> 4) << 3) + j;
    int chunk = kp / 96, kq = kp % 96;
    int t = kq >> 3, c = kq & 7;
    int n = nt * 16 + (l & 15);
    float v = (t < 9) ? cw[n * 576 + (chunk * 8 + c) * 9 + t] : 0.f;
    Bp[i] = bf16bits(v);
  }
  if (i < 24576) {                      // offconv weights, nt 0..1, n<18
    int j = i & 7, l = (i >> 3) & 63, rest = i >> 9;
    int ki = rest % 24, nt = rest / 24;
    int kp = ki * 32 + ((l >> 4) << 3) + j;
    int chunk = kp / 96, kq = kp % 96;
    int t = kq >> 3, c = kq & 7;
    int n = nt * 16 + (l & 15);
    float v = (t < 9 && n < 18) ? ow[n * 576 + (chunk * 8 + c) * 9 + t] : 0.f;
    B2p[i] = bf16bits(v);
  }
}

// ---------------------------------------------------------------------------
// FUSED offconv + dconv.
// Phase 1 (offconv): implicit GEMM M=64 (16x4), N=32 (18 used), K=576 pad
// 768 over d. Clamped offsets go to global off_out (required output) AND to
// a 64x18 LDS array consumed by phase 2 -- no inter-kernel round trip.
// Phase 2 (dconv): implicit GEMM M=64, N=64, K=576 pad 768 over x, with
// bilinear sampling from a channel-interleaved LDS patch, BN partial sums
// fused into the epilogue.
// Grid 1600 (1D, XCD-slab swizzled). LDS = patch 9072 + Af 12288 + offs 4608
// = 25968 B -> 6 blocks/CU.
// ---------------------------------------------------------------------------
__global__ __launch_bounds__(256, 4) void fused_kernel(
    const float* __restrict__ x, const float* __restrict__ d,
    const bf16x8* __restrict__ Bp, const bf16x8* __restrict__ B2p,
    float* __restrict__ out, float* __restrict__ off_out,
    float* __restrict__ part) {
  int b, ty0, tx0;
  tile_map(blockIdx.x, b, ty0, tx0);
  const int tid = threadIdx.x;
  const int wv = tid >> 6, lane = tid & 63;
  const int lo = lane >> 4, li = lane & 15;
  const int px = li, py = wv;
  const int h = ty0 + py, w = tx0 + px;

  __shared__ float patch[189 * 12];    // phase1: 108x12 region; phase2: full
  __shared__ bf16x8 Af[768];
  __shared__ float offs_s[64 * 18];    // per-pixel 9 taps x (dy,dx)

  // ---- phase-2 x-staging addresses precomputed (held through phase 1 so
  //      the first x chunk loads can issue under the phase-1 epilogue) ----
  int goffx[6], laddrx[6];
  bool gokx[6];
#pragma unroll
  for (int i = 0; i < 6; ++i) {
    int l = tid + i * 256;
    int c = l / 189, rc = l % 189, r = rc / 21, col = rc % 21;
    int gy = ty0 - 2 + r, gx = tx0 - 2 + col;
    gokx[i] = (l < 1512) && gy >= 0 && gy < HH && gx >= 0 && gx < WW;
    goffx[i] = ((b * 64 + c) * HH + gy) * WW + gx;
    laddrx[i] = rc * 12 + c;
  }

  // ================= phase 1: offconv =================
  f32x4 acc0{0.f, 0.f, 0.f, 0.f}, acc1{0.f, 0.f, 0.f, 0.f};
  const int ntA = wv >> 1, mh = wv & 1;
  {
    int poff[3];
    bool tre[3];
#pragma unroll
    for (int kk = 0; kk < 3; ++kk) {
      int t = kk * 4 + lo;
      tre[kk] = (t < 9);
      poff[kk] = tre[kk] ? ((py + t / 3) * 18 + px + t % 3) : 0;
    }

    int goff[4], laddr[4];
    bool gok[4];
#pragma unroll
    for (int i = 0; i < 4; ++i) {
      int l = tid + i * 256;
      int c = l / 108, rc = l % 108, r = rc / 18, col = rc % 18;
      int gy = ty0 - 1 + r, gx = tx0 - 1 + col;
      gok[i] = (l < 864) && gy >= 0 && gy < HH && gx < WW && gx >= 0;
      goff[i] = ((b * 64 + c) * HH + gy) * WW + gx;
      laddr[i] = rc * 12 + c;
    }
    float g[4];
#pragma unroll
    for (int i = 0; i < 4; ++i) g[i] = gok[i] ? d[goff[i]] : 0.f;

    for (int chunk = 0; chunk < 8; ++chunk) {
      bf16x8 bw0 = B2p[((ntA * 24 + chunk * 3 + 0) << 6) + lane];
      bf16x8 bw1 = B2p[((ntA * 24 + chunk * 3 + 1) << 6) + lane];
      bf16x8 bw2 = B2p[((ntA * 24 + chunk * 3 + 2) << 6) + lane];
#pragma unroll
      for (int i = 0; i < 4; ++i) {
        int l = tid + i * 256;
        if (l < 864) patch[laddr[i]] = g[i];
      }
      __syncthreads();
      int nco = ((chunk < 7) ? (chunk + 1) : 7) * CHSTRIDE;
#pragma unroll
      for (int i = 0; i < 4; ++i) g[i] = gok[i] ? d[goff[i] + nco] : 0.f;
#pragma unroll
      for (int kk = 0; kk < 3; ++kk) {
        union { bf16x8 v; unsigned u[4]; } a;
        if (tre[kk]) {
          const float* q = patch + poff[kk] * 12;
          float4 c0 = *(const float4*)(q);
          float4 c1 = *(const float4*)(q + 4);
          a.u[0] = pack2bf(c0.x, c0.y);
          a.u[1] = pack2bf(c0.z, c0.w);
          a.u[2] = pack2bf(c1.x, c1.y);
          a.u[3] = pack2bf(c1.z, c1.w);
        } else {
          a.u[0] = a.u[1] = a.u[2] = a.u[3] = 0u;
        }
        Af[((wv * 3 + kk) << 6) + lane] = a.v;
      }
      __syncthreads();
#pragma unroll
      for (int kk = 0; kk < 3; ++kk) {
        bf16x8 bw = (kk == 0) ? bw0 : (kk == 1) ? bw1 : bw2;
        acc0 = __builtin_amdgcn_mfma_f32_16x16x32_bf16(
            Af[(((mh * 2) * 3 + kk) << 6) + lane], bw, acc0, 0, 0, 0);
        acc1 = __builtin_amdgcn_mfma_f32_16x16x32_bf16(
            Af[(((mh * 2 + 1) * 3 + kk) << 6) + lane], bw, acc1, 0, 0, 0);
      }
    }
  }

  // issue the first x chunk now: HBM latency hides under the phase-1
  // epilogue + inter-phase barrier + offset unpack
  float gv[6];
#pragma unroll
  for (int i = 0; i < 6; ++i) gv[i] = gokx[i] ? x[goffx[i]] : 0.f;

  {  // phase-1 epilogue: clamp, write global off_out + LDS offs_s
    const int n = ntA * 16 + li;
    if (n < 18) {
#pragma unroll
      for (int f = 0; f < 2; ++f) {
        int mf = mh * 2 + f;
        f32x4 a = f ? acc1 : acc0;
        float* po =
            off_out + ((b * 18 + n) * HH + ty0 + mf) * WW + tx0 + lo * 4;
        float4 v;
        v.x = fminf(1.f, fmaxf(-1.f, a[0]));
        v.y = fminf(1.f, fmaxf(-1.f, a[1]));
        v.z = fminf(1.f, fmaxf(-1.f, a[2]));
        v.w = fminf(1.f, fmaxf(-1.f, a[3]));
        *(float4*)po = v;
        int pix = mf * 16 + lo * 4;
        offs_s[(pix + 0) * 18 + n] = v.x;
        offs_s[(pix + 1) * 18 + n] = v.y;
        offs_s[(pix + 2) * 18 + n] = v.z;
        offs_s[(pix + 3) * 18 + n] = v.w;
      }
    }
  }
  __syncthreads();

  // ================= phase 2: dconv =================
  int bs[3];
  float W00[3], W01[3], W10[3], W11[3];
  bool tre[3];
#pragma unroll
  for (int kk = 0; kk < 3; ++kk) {
    int t = kk * 4 + lo;
    tre[kk] = (t < 9);
    if (tre[kk]) {
      float dy = offs_s[(py * 16 + px) * 18 + 2 * t];
      float dx = offs_s[(py * 16 + px) * 18 + 2 * t + 1];
      float pyf = (float)(h - 1 + t / 3) + dy;
      float pxf = (float)(w - 1 + t % 3) + dx;
      float y0 = floorf(pyf), x0 = floorf(pxf);
      float wy = pyf - y0, wx = pxf - x0;
      bs[kk] = ((int)y0 - (ty0 - 2)) * 21 + ((int)x0 - (tx0 - 2));
      W00[kk] = (1.f - wy) * (1.f - wx);
      W01[kk] = (1.f - wy) * wx;
      W10[kk] = wy * (1.f - wx);
      W11[kk] = wy * wx;
    } else {
      bs[kk] = 0;
      W00[kk] = W01[kk] = W10[kk] = W11[kk] = 0.f;
    }
  }

  f32x4 acc[4];
#pragma unroll
  for (int i = 0; i < 4; ++i) acc[i] = f32x4{0.f, 0.f, 0.f, 0.f};
  const int nt = wv;

  for (int chunk = 0; chunk < 8; ++chunk) {
    bf16x8 bw0 = Bp[((nt * 24 + chunk * 3 + 0) << 6) + lane];
    bf16x8 bw1 = Bp[((nt * 24 + chunk * 3 + 1) << 6) + lane];
    bf16x8 bw2 = Bp[((nt * 24 + chunk * 3 + 2) << 6) + lane];
#pragma unroll
    for (int i = 0; i < 6; ++i) {
      int l = tid + i * 256;
      if (l < 1512) patch[laddrx[i]] = gv[i];
    }
    __syncthreads();
    int nco = ((chunk < 7) ? (chunk + 1) : 7) * CHSTRIDE;
#pragma unroll
    for (int i = 0; i < 6; ++i) gv[i] = gokx[i] ? x[goffx[i] + nco] : 0.f;
#pragma unroll
    for (int kk = 0; kk < 3; ++kk) {
      union { bf16x8 v; unsigned u[4]; } a;
      if (tre[kk]) {
        const float* q = patch + bs[kk] * 12;
        float4 p00a = *(const float4*)(q);         // corner (0,0) ch0-3
        float4 p00b = *(const float4*)(q + 4);     //            ch4-7
        float4 p01a = *(const float4*)(q + 12);    // corner (0,1)
        float4 p01b = *(const float4*)(q + 16);
        float4 p10a = *(const float4*)(q + 252);   // corner (1,0): +21*12
        float4 p10b = *(const float4*)(q + 256);
        float4 p11a = *(const float4*)(q + 264);   // corner (1,1)
        float4 p11b = *(const float4*)(q + 268);
        float w0 = W00[kk], w1 = W01[kk], w2 = W10[kk], w3 = W11[kk];
        float v0 = fmaf(w3, p11a.x, fmaf(w2, p10a.x, fmaf(w1, p01a.x, w0 * p00a.x)));
        float v1 = fmaf(w3, p11a.y, fmaf(w2, p10a.y, fmaf(w1, p01a.y, w0 * p00a.y)));
        float v2 = fmaf(w3, p11a.z, fmaf(w2, p10a.z, fmaf(w1, p01a.z, w0 * p00a.z)));
        float v3 = fmaf(w3, p11a.w, fmaf(w2, p10a.w, fmaf(w1, p01a.w, w0 * p00a.w)));
        float v4 = fmaf(w3, p11b.x, fmaf(w2, p10b.x, fmaf(w1, p01b.x, w0 * p00b.x)));
        float v5 = fmaf(w3, p11b.y, fmaf(w2, p10b.y, fmaf(w1, p01b.y, w0 * p00b.y)));
        float v6 = fmaf(w3, p11b.z, fmaf(w2, p10b.z, fmaf(w1, p01b.z, w0 * p00b.z)));
        float v7 = fmaf(w3, p11b.w, fmaf(w2, p10b.w, fmaf(w1, p01b.w, w0 * p00b.w)));
        a.u[0] = pack2bf(v0, v1);
        a.u[1] = pack2bf(v2, v3);
        a.u[2] = pack2bf(v4, v5);
        a.u[3] = pack2bf(v6, v7);
      } else {
        a.u[0] = a.u[1] = a.u[2] = a.u[3] = 0u;
      }
      Af[((wv * 3 + kk) << 6) + lane] = a.v;
    }
    __syncthreads();
#pragma unroll
    for (int kk = 0; kk < 3; ++kk) {
      bf16x8 bw = (kk == 0) ? bw0 : (kk == 1) ? bw1 : bw2;
#pragma unroll
      for (int mf = 0; mf < 4; ++mf)
        acc[mf] = __builtin_amdgcn_mfma_f32_16x16x32_bf16(
            Af[((mf * 3 + kk) << 6) + lane], bw, acc[mf], 0, 0, 0);
    }
  }
  // epilogue: aligned float4 stores + fused BN partial sums
  const int n = nt * 16 + li;
  float s = 0.f, s2 = 0.f;
#pragma unroll
  for (int mf = 0; mf < 4; ++mf) {
    float* po = out + ((b * 64 + n) * HH + ty0 + mf) * WW + tx0 + lo * 4;
    *(float4*)po = make_float4(acc[mf][0], acc[mf][1], acc[mf][2], acc[mf][3]);
#pragma unroll
    for (int r = 0; r < 4; ++r) {
      float v = acc[mf][r];
      s += v;
      s2 = fmaf(v, v, s2);
    }
  }
  // reduce across the 4 lanes (lo=0..3) holding channel n
  s += __shfl_xor(s, 16);  s += __shfl_xor(s, 32);
  s2 += __shfl_xor(s2, 16); s2 += __shfl_xor(s2, 32);
  if (lo == 0) {
    int slot = blockIdx.x & (NSLOT - 1);
    atomicAdd(&part[n * NSLOT + slot], s);
    atomicAdd(&part[(64 + n) * NSLOT + slot], s2);
  }
}

// ---------------------------------------------------------------------------
// reduce BN partials: block j sums part[j][0..255] (f64) -> sums[j]
// ---------------------------------------------------------------------------
__global__ __launch_bounds__(256) void reduce_kernel(
    const float* __restrict__ part, double* __restrict__ sums) {
  const int j = blockIdx.x;
  __shared__ double sh[256];
  sh[threadIdx.x] = (double)part[j * NSLOT + threadIdx.x];
  __syncthreads();
  for (int t = 128; t > 0; t >>= 1) {
    if (threadIdx.x < t) sh[threadIdx.x] += sh[threadIdx.x + t];
    __syncthreads();
  }
  if (threadIdx.x == 0) sums[j] = sh[0];
}

// ---------------------------------------------------------------------------
// BN apply + ReLU, in place on d_out's conv region (float4 vectorized).
// ---------------------------------------------------------------------------
__global__ __launch_bounds__(256) void bnapply_kernel(
    float* __restrict__ out, const double* __restrict__ sums,
    const float* __restrict__ gamma, const float* __restrict__ beta) {
  const int i = blockIdx.x * 256 + threadIdx.x;
  if (i >= OUT_ELEMS / 4) return;
  const int o = (i / (HWD / 4)) & 63;
  const float n_inv = 1.0f / (float)(BB * HWD);
  float mean = (float)sums[o] * n_inv;
  float var = (float)sums[64 + o] * n_inv - mean * mean;
  float inv = gamma[o] * rsqrtf(var + EPSBN);
  float bt = beta[o];
  float4 v = ((float4*)out)[i];
  v.x = fmaxf(0.f, (v.x - mean) * inv + bt);
  v.y = fmaxf(0.f, (v.y - mean) * inv + bt);
  v.z = fmaxf(0.f, (v.z - mean) * inv + bt);
  v.w = fmaxf(0.f, (v.w - mean) * inv + bt);
  ((float4*)out)[i] = v;
}

extern "C" void kernel_launch(void* const* d_in, const int* in_sizes, int n_in,
                              void* d_out, int out_size, void* d_ws, size_t ws_size,
                              hipStream_t stream) {
  const float* x = (const float*)d_in[0];
  const float* d = (const float*)d_in[1];
  const float* ow = (const float*)d_in[2];
  const float* cw = (const float*)d_in[3];
  const float* gamma = (const float*)d_in[4];
  const float* beta = (const float*)d_in[5];

  float* out = (float*)d_out;
  float* off_out = out + OUT_ELEMS;

  // ws: sums double[128] | Bp ush[49152] | B2p ush[24576] | part f32[32768]
  double* sums = (double*)d_ws;
  unsigned short* Bp = (unsigned short*)((char*)d_ws + 1024);
  unsigned short* B2p = Bp + 49152;
  float* part = (float*)(B2p + 24576);

  prep_kernel<<<192, 256, 0, stream>>>(cw, ow, Bp, B2p, part);

  fused_kernel<<<1600, 256, 0, stream>>>(x, d, (const bf16x8*)Bp,
                                         (const bf16x8*)B2p, out, off_out,
                                         part);

  reduce_kernel<<<128, 256, 0, stream>>>(part, sums);
  bnapply_kernel<<<(OUT_ELEMS / 4 + 255) / 256, 256, 0, stream>>>(
      out, sums, gamma, beta);
}